// Round 11
// baseline (353.704 us; speedup 1.0000x reference)
//
#include <hip/hip_runtime.h>

typedef unsigned short u16;
typedef __attribute__((ext_vector_type(8))) short bf16x8;
typedef __attribute__((ext_vector_type(4))) float f32x4;

#define SEQ 4096
#define DIM 1024

// ---------- bf16 helpers (OCP bf16 = top 16 bits of fp32, RNE) ----------
__device__ __forceinline__ u16 f2bf(float f) {
  unsigned u = __float_as_uint(f);
  return (u16)((u + 0x7fffu + ((u >> 16) & 1u)) >> 16);
}
__device__ __forceinline__ float bf2f(u16 h) {
  return __uint_as_float(((unsigned)h) << 16);
}

// ---------- async global->LDS, 16B per lane ----------
__device__ __forceinline__ void gload_lds16(const void* g, void* l) {
  __builtin_amdgcn_global_load_lds(
      (const __attribute__((address_space(1))) void*)g,
      (__attribute__((address_space(3))) void*)l, 16, 0, 0);
}

// ---------- tile-packed operand layout (r4/r7-verified: 0 bank conflicts) ----------
// Matrix [R][Kd] stored as 128x32 tiles; tile (rb,kb) at (rb*(Kd/32)+kb)*4096.
// Within tile, 16B slot s = ((r7>>4)<<6) | ((c5>>3)<<4) | (r7&15), elem = c5&7.
__device__ __forceinline__ size_t pkoff(int row, int col, int kd) {
  int tile = (row >> 7) * (kd >> 5) + (col >> 5);
  int r7 = row & 127, c5 = col & 31;
  int slot = ((r7 >> 4) << 6) | ((c5 >> 3) << 4) | (r7 & 15);
  return (size_t)tile * 4096 + (size_t)(slot * 8 + (c5 & 7));
}

// stage one packed 128x32 tile (4096 elems, contiguous) into LDS
__device__ __forceinline__ void stage_tile_pk(const u16* __restrict__ g,
                                              u16* lds, int tid) {
  const int w = tid >> 6;
  gload_lds16(g + (size_t)tid * 8, lds + (size_t)(w * 64) * 8);
  gload_lds16(g + (size_t)(256 + tid) * 8, lds + (size_t)(256 + w * 64) * 8);
}

// ---------- fused 3-pair NT GEMM core, double-buffered (2 x 32KB LDS) ----------
// r7-proven: 16x16x32, 4x4 per wave (16 chains). Used by qk.
__device__ __forceinline__ void gemm3_db(
    const u16* A0, const u16* A1, const u16* B0, const u16* B1,
    int nkb, u16* lds, f32x4 (&acc)[4][4]) {
  const int tid = threadIdx.x;
  const int w = tid >> 6, l = tid & 63;
  const int wm = w >> 1, wn = w & 1;

#pragma unroll
  for (int mi = 0; mi < 4; ++mi)
#pragma unroll
    for (int ni = 0; ni < 4; ++ni)
      acc[mi][ni] = (f32x4){0.f, 0.f, 0.f, 0.f};

  const int ao = wm * 2048 + l * 8;
  const int bo = wn * 2048 + l * 8;

  stage_tile_pk(A0, lds, tid);
  stage_tile_pk(B0, lds + 4096, tid);
  stage_tile_pk(A1, lds + 8192, tid);
  stage_tile_pk(B1, lds + 12288, tid);

  for (int kb = 0; kb < nkb; ++kb) {
    __syncthreads();
    if (kb + 1 < nkb) {
      u16* nb = lds + ((kb + 1) & 1) * 16384;
      const size_t off = (size_t)(kb + 1) * 4096;
      stage_tile_pk(A0 + off, nb, tid);
      stage_tile_pk(B0 + off, nb + 4096, tid);
      stage_tile_pk(A1 + off, nb + 8192, tid);
      stage_tile_pk(B1 + off, nb + 12288, tid);
    }
    const u16* cb = lds + (kb & 1) * 16384;
    const u16* lA0 = cb;
    const u16* lB0 = cb + 4096;
    const u16* lA1 = cb + 8192;
    const u16* lB1 = cb + 12288;

    bf16x8 a0[4], b0[4];
#pragma unroll
    for (int i = 0; i < 4; ++i) {
      a0[i] = *(const bf16x8*)(lA0 + ao + i * 512);
      b0[i] = *(const bf16x8*)(lB0 + bo + i * 512);
    }
#pragma unroll
    for (int mi = 0; mi < 4; ++mi)
#pragma unroll
      for (int ni = 0; ni < 4; ++ni)
        acc[mi][ni] = __builtin_amdgcn_mfma_f32_16x16x32_bf16(
            a0[mi], b0[ni], acc[mi][ni], 0, 0, 0);
    bf16x8 b1[4];
#pragma unroll
    for (int i = 0; i < 4; ++i) b1[i] = *(const bf16x8*)(lB1 + bo + i * 512);
#pragma unroll
    for (int mi = 0; mi < 4; ++mi)
#pragma unroll
      for (int ni = 0; ni < 4; ++ni)
        acc[mi][ni] = __builtin_amdgcn_mfma_f32_16x16x32_bf16(
            a0[mi], b1[ni], acc[mi][ni], 0, 0, 0);
    bf16x8 a1[4];
#pragma unroll
    for (int i = 0; i < 4; ++i) a1[i] = *(const bf16x8*)(lA1 + ao + i * 512);
#pragma unroll
    for (int mi = 0; mi < 4; ++mi)
#pragma unroll
      for (int ni = 0; ni < 4; ++ni)
        acc[mi][ni] = __builtin_amdgcn_mfma_f32_16x16x32_bf16(
            a1[mi], b0[ni], acc[mi][ni], 0, 0, 0);
  }
  __syncthreads();
}

// ---------- single-pair NT GEMM core, BK=64, double-buffered (2 x 32KB) ----------
__device__ __forceinline__ void gemm1_db(
    const u16* A, const u16* B, int nkb, u16* lds, f32x4 (&acc)[4][4]) {
  const int tid = threadIdx.x;
  const int w = tid >> 6, l = tid & 63;
  const int wm = w >> 1, wn = w & 1;

#pragma unroll
  for (int mi = 0; mi < 4; ++mi)
#pragma unroll
    for (int ni = 0; ni < 4; ++ni)
      acc[mi][ni] = (f32x4){0.f, 0.f, 0.f, 0.f};

  const int ao = wm * 2048 + l * 8;
  const int bo = wn * 2048 + l * 8;
  const int nit = nkb >> 1;

  stage_tile_pk(A, lds, tid);
  stage_tile_pk(A + 4096, lds + 4096, tid);
  stage_tile_pk(B, lds + 8192, tid);
  stage_tile_pk(B + 4096, lds + 12288, tid);

  for (int it = 0; it < nit; ++it) {
    __syncthreads();
    if (it + 1 < nit) {
      u16* nb = lds + ((it + 1) & 1) * 16384;
      const size_t off = (size_t)(it + 1) * 8192;
      stage_tile_pk(A + off, nb, tid);
      stage_tile_pk(A + off + 4096, nb + 4096, tid);
      stage_tile_pk(B + off, nb + 8192, tid);
      stage_tile_pk(B + off + 4096, nb + 12288, tid);
    }
    const u16* cb = lds + (it & 1) * 16384;
#pragma unroll
    for (int ht = 0; ht < 2; ++ht) {
      bf16x8 av[4], bv[4];
#pragma unroll
      for (int i = 0; i < 4; ++i) {
        av[i] = *(const bf16x8*)(cb + ht * 4096 + ao + i * 512);
        bv[i] = *(const bf16x8*)(cb + 8192 + ht * 4096 + bo + i * 512);
      }
#pragma unroll
      for (int mi = 0; mi < 4; ++mi)
#pragma unroll
        for (int ni = 0; ni < 4; ++ni)
          acc[mi][ni] = __builtin_amdgcn_mfma_f32_16x16x32_bf16(
              av[mi], bv[ni], acc[mi][ni], 0, 0, 0);
    }
  }
  __syncthreads();
}

// C/D layout (m89/m91 verified): lane l, reg r -> row=(l>>4)*4+r, col=l&15
#define EPILOGUE_IDX                                          \
  const int tid = threadIdx.x, w = tid >> 6, l = tid & 63;    \
  const int wm = w >> 1, wn = w & 1, lr = l & 15, q = l >> 4; \
  (void)tid;

// ---------- epilogue repack: C regs -> packed bf16 h/l via LDS ----------
__device__ __forceinline__ void epilogue_pack(
    f32x4 (&acc)[4][4], u16* lds, int row0, int col0, int kd,
    u16* __restrict__ H, u16* __restrict__ L) {
  const int tid = threadIdx.x, w = tid >> 6, l = tid & 63;
  const int wm = w >> 1, wn = w & 1, lr = l & 15, q = l >> 4;
  float* lC = (float*)lds;
#pragma unroll
  for (int hh = 0; hh < 2; ++hh) {
    if (wm == hh) {
#pragma unroll
      for (int mi = 0; mi < 4; ++mi)
#pragma unroll
        for (int ni = 0; ni < 4; ++ni)
#pragma unroll
          for (int r = 0; r < 4; ++r)
            lC[(mi * 16 + q * 4 + r) * 132 + wn * 64 + ni * 16 + lr] =
                acc[mi][ni][r];
    }
    __syncthreads();
#pragma unroll
    for (int j = 0; j < 2; ++j) {
      int c = tid + 256 * j;
      int row = c >> 3, c0 = (c & 7) * 16;
      u16 hbuf[16], lbuf[16];
#pragma unroll
      for (int i = 0; i < 16; ++i) {
        float v = lC[row * 132 + c0 + i];
        u16 hv = f2bf(v);
        hbuf[i] = hv;
        lbuf[i] = f2bf(v - bf2f(hv));
      }
      int rg = row0 + hh * 64 + row;
      size_t o0 = pkoff(rg, col0 + c0, kd);
      size_t o1 = pkoff(rg, col0 + c0 + 8, kd);
      *(bf16x8*)(H + o0) = *(bf16x8*)(hbuf);
      *(bf16x8*)(H + o1) = *(bf16x8*)(hbuf + 8);
      if (L) {
        *(bf16x8*)(L + o0) = *(bf16x8*)(lbuf);
        *(bf16x8*)(L + o1) = *(bf16x8*)(lbuf + 8);
      }
    }
    if (hh == 0) __syncthreads();
  }
}

// ---------- kernels ----------

__global__ __launch_bounds__(256) void prep_kernel(
    const float* __restrict__ X,
    const float* __restrict__ W0, const float* __restrict__ W1, const float* __restrict__ W2,
    u16* __restrict__ Xh, u16* __restrict__ Xl,
    u16* __restrict__ H0, u16* __restrict__ L0,
    u16* __restrict__ H1, u16* __restrict__ L1,
    u16* __restrict__ H2) {
  const int z = blockIdx.z;
  const int tx = threadIdx.x, ty = threadIdx.y;
  if (z == 0) {
    int idx = (blockIdx.y * 32 + blockIdx.x) * 256 + ty * 32 + tx;
    int row = idx >> 6;
    int c0 = (idx & 63) * 16;
    u16 h[16], lo[16];
#pragma unroll
    for (int j = 0; j < 4; ++j) {
      float4 x = *(const float4*)(X + (size_t)row * DIM + c0 + j * 4);
      float v;
      v = x.x; h[j*4+0] = f2bf(v); lo[j*4+0] = f2bf(v - bf2f(h[j*4+0]));
      v = x.y; h[j*4+1] = f2bf(v); lo[j*4+1] = f2bf(v - bf2f(h[j*4+1]));
      v = x.z; h[j*4+2] = f2bf(v); lo[j*4+2] = f2bf(v - bf2f(h[j*4+2]));
      v = x.w; h[j*4+3] = f2bf(v); lo[j*4+3] = f2bf(v - bf2f(h[j*4+3]));
    }
    size_t o0 = pkoff(row, c0, DIM);
    size_t o1 = pkoff(row, c0 + 8, DIM);
    *(bf16x8*)(Xh + o0) = *(bf16x8*)(h);
    *(bf16x8*)(Xl + o0) = *(bf16x8*)(lo);
    *(bf16x8*)(Xh + o1) = *(bf16x8*)(h + 8);
    *(bf16x8*)(Xl + o1) = *(bf16x8*)(lo + 8);
    return;
  }
  __shared__ float t[32][33];
  const float* W = (z == 1) ? W0 : (z == 2) ? W1 : W2;
  u16* H = (z == 1) ? H0 : (z == 2) ? H1 : H2;
  u16* L = (z == 1) ? L0 : (z == 2) ? L1 : nullptr;
  const int i0 = blockIdx.y * 32, o0 = blockIdx.x * 32;
#pragma unroll
  for (int m = 0; m < 4; ++m)
    t[ty + 8 * m][tx] = W[(size_t)(i0 + ty + 8 * m) * DIM + o0 + tx];
  __syncthreads();
#pragma unroll
  for (int m = 0; m < 4; ++m) {
    float v = t[tx][ty + 8 * m];
    u16 h = f2bf(v);
    size_t o = pkoff(o0 + ty + 8 * m, i0 + tx, DIM);
    H[o] = h;
    if (L) L[o] = f2bf(v - bf2f(h));
  }
}

// z=0: Q = X Wq (split, packed out)  z=1: K likewise
// z=2: VT = Wv^T X^T (bf16, packed out, rows over DIM, Kd=SEQ)
__global__ __launch_bounds__(256) void qkv_kernel(
    const u16* __restrict__ Xh, const u16* __restrict__ Xl,
    const u16* __restrict__ Wh0, const u16* __restrict__ Wl0,
    const u16* __restrict__ Wh1, const u16* __restrict__ Wl1,
    const u16* __restrict__ Wh2,
    u16* __restrict__ Qh, u16* __restrict__ Ql,
    u16* __restrict__ Kh, u16* __restrict__ Kl,
    u16* __restrict__ VT) {
  __shared__ __align__(16) u16 lds[2 * 4 * 4096];
  const int z = blockIdx.z;
  f32x4 acc[4][4];
  if (z < 2) {
    const u16* Wh = z ? Wh1 : Wh0;
    const u16* Wl = z ? Wl1 : Wl0;
    const int row0 = blockIdx.y * 128, col0 = blockIdx.x * 128;
    gemm3_db(Xh + (size_t)row0 * DIM, Xl + (size_t)row0 * DIM,
             Wh + (size_t)col0 * DIM, Wl + (size_t)col0 * DIM,
             DIM / 32, lds, acc);
    epilogue_pack(acc, lds, row0, col0, DIM, z ? Kh : Qh, z ? Kl : Ql);
  } else {
    const int row0 = blockIdx.x * 128;  // over DIM
    const int col0 = blockIdx.y * 128;  // over SEQ
    gemm1_db(Wh2 + (size_t)row0 * DIM, Xh + (size_t)col0 * DIM,
             DIM / 32, lds, acc);
    epilogue_pack(acc, lds, row0, col0, SEQ, VT, nullptr);
  }
}

// ---------- S = (Q K^T)/32: NEW 128x256-tile single-buffer ratio-4 core ----------
// 4 waves, wave tile 64x128 (wm=row half, wn=col half of 256).
// Per wave-iter: 24 ds_read_b128 for 96 MFMA (ratio 4.0 vs r7's 3.0); 96 MFMA
// per barrier (~466 cyc) amortizes the stage drain 2x; 512 blocks = 2/CU gives
// cross-block overlap (m114) in place of dbuf (6 tiles = 48KB; dbuf won't fit).
__global__ __launch_bounds__(256) void s_kernel(
    const u16* __restrict__ Qh, const u16* __restrict__ Ql,
    const u16* __restrict__ Kh, const u16* __restrict__ Kl,
    float* __restrict__ S) {
  __shared__ __align__(16) u16 lds[6 * 4096];  // 48 KB
  const int tid = threadIdx.x;
  const int w = tid >> 6, l = tid & 63;
  const int wm = w >> 1, wn = w & 1;
  const int lr = l & 15, q = l >> 4;
  const int row0 = blockIdx.y * 128;   // over Q rows
  const int col0 = blockIdx.x * 256;   // over K rows (S cols)

  const u16* A0 = Qh + (size_t)row0 * DIM;   // 1 tile/kb
  const u16* A1 = Ql + (size_t)row0 * DIM;
  const u16* B0 = Kh + (size_t)col0 * DIM;   // 2 tiles/kb (256 cols)
  const u16* B1 = Kl + (size_t)col0 * DIM;
  const int nkb = DIM / 32;                  // 32; B tile (c,kb) at (c*nkb+kb)*4096

  f32x4 acc[4][8];
#pragma unroll
  for (int mi = 0; mi < 4; ++mi)
#pragma unroll
    for (int ni = 0; ni < 8; ++ni) acc[mi][ni] = (f32x4){0.f, 0.f, 0.f, 0.f};

  const int aoff = wm * 2048 + l * 8;        // a frag mi: + mi*512
  const int boff = wn * 4096 + l * 8;        // b frag ni: + ni*512 (within 2-tile panel)

  for (int kb = 0; kb < nkb; ++kb) {
    const size_t tk = (size_t)kb * 4096;
    stage_tile_pk(A0 + tk, lds, tid);
    stage_tile_pk(A1 + tk, lds + 4096, tid);
    stage_tile_pk(B0 + tk, lds + 8192, tid);
    stage_tile_pk(B0 + (size_t)nkb * 4096 + tk, lds + 12288, tid);
    stage_tile_pk(B1 + tk, lds + 16384, tid);
    stage_tile_pk(B1 + (size_t)nkb * 4096 + tk, lds + 20480, tid);
    __syncthreads();  // vmcnt(0): all 6 tiles ready

    bf16x8 a0[4], a1[4], b0[8];
#pragma unroll
    for (int i = 0; i < 4; ++i) {
      a0[i] = *(const bf16x8*)(lds + aoff + i * 512);
      a1[i] = *(const bf16x8*)(lds + 4096 + aoff + i * 512);
    }
#pragma unroll
    for (int i = 0; i < 8; ++i)
      b0[i] = *(const bf16x8*)(lds + 8192 + boff + i * 512);
    // hh + lh passes (both consume b0)
#pragma unroll
    for (int mi = 0; mi < 4; ++mi)
#pragma unroll
      for (int ni = 0; ni < 8; ++ni)
        acc[mi][ni] = __builtin_amdgcn_mfma_f32_16x16x32_bf16(
            a0[mi], b0[ni], acc[mi][ni], 0, 0, 0);
#pragma unroll
    for (int mi = 0; mi < 4; ++mi)
#pragma unroll
      for (int ni = 0; ni < 8; ++ni)
        acc[mi][ni] = __builtin_amdgcn_mfma_f32_16x16x32_bf16(
            a1[mi], b0[ni], acc[mi][ni], 0, 0, 0);
    // hl pass (b0 dead -> b1)
    bf16x8 b1[8];
#pragma unroll
    for (int i = 0; i < 8; ++i)
      b1[i] = *(const bf16x8*)(lds + 16384 + boff + i * 512);
#pragma unroll
    for (int mi = 0; mi < 4; ++mi)
#pragma unroll
      for (int ni = 0; ni < 8; ++ni)
        acc[mi][ni] = __builtin_amdgcn_mfma_f32_16x16x32_bf16(
            a0[mi], b1[ni], acc[mi][ni], 0, 0, 0);
    __syncthreads();  // reads done before next stage overwrites
  }

  const float scale = 0.03125f;  // 1/sqrt(1024)
#pragma unroll
  for (int mi = 0; mi < 4; ++mi)
#pragma unroll
    for (int ni = 0; ni < 8; ++ni)
#pragma unroll
      for (int r = 0; r < 4; ++r) {
        int row = row0 + wm * 64 + mi * 16 + q * 4 + r;
        int col = col0 + wn * 128 + ni * 16 + lr;
        S[(size_t)row * SEQ + col] = acc[mi][ni][r] * scale;
      }
}

// row softmax: S fp32 [4096][4096] -> P bf16 tile-packed (Kd=SEQ)
__global__ __launch_bounds__(256) void softmax_kernel(const float* __restrict__ S,
                                                      u16* __restrict__ P) {
  const int row = blockIdx.x;
  const float* s = S + (size_t)row * SEQ;
  const int tid = threadIdx.x;
  const int c0 = tid * 16;
  float v[16];
  float mx = -3.4e38f;
#pragma unroll
  for (int j = 0; j < 4; ++j) {
    float4 x = *(const float4*)(s + c0 + j * 4);
    v[j * 4 + 0] = x.x; v[j * 4 + 1] = x.y; v[j * 4 + 2] = x.z; v[j * 4 + 3] = x.w;
    mx = fmaxf(mx, fmaxf(fmaxf(x.x, x.y), fmaxf(x.z, x.w)));
  }
#pragma unroll
  for (int off = 32; off; off >>= 1) mx = fmaxf(mx, __shfl_xor(mx, off));
  __shared__ float red[8];
  const int w = tid >> 6, l = tid & 63;
  if (l == 0) red[w] = mx;
  __syncthreads();
  mx = fmaxf(fmaxf(red[0], red[1]), fmaxf(red[2], red[3]));
  float sum = 0.f;
#pragma unroll
  for (int i = 0; i < 16; ++i) {
    v[i] = __expf(v[i] - mx);
    sum += v[i];
  }
#pragma unroll
  for (int off = 32; off; off >>= 1) sum += __shfl_xor(sum, off);
  if (l == 0) red[4 + w] = sum;
  __syncthreads();
  sum = red[4] + red[5] + red[6] + red[7];
  const float inv = 1.f / sum;
  u16 p[16];
#pragma unroll
  for (int i = 0; i < 16; ++i) p[i] = f2bf(v[i] * inv);
  *(bf16x8*)(P + pkoff(row, c0, SEQ)) = *(bf16x8*)(p);
  *(bf16x8*)(P + pkoff(row, c0 + 8, SEQ)) = *(bf16x8*)(p + 8);
}

// O partial = P[:, z*2048:(z+1)*2048] @ V[...]  (split-K=2, packed, BK=64, dbuf)
__global__ __launch_bounds__(256) void o_kernel(const u16* __restrict__ P,
                                                const u16* __restrict__ VT,
                                                float* __restrict__ Opart) {
  __shared__ __align__(16) u16 lds[2 * 4 * 4096];
  const int z = blockIdx.z;
  const int row0 = blockIdx.y * 128, col0 = blockIdx.x * 128;
  const u16* A = P + (size_t)row0 * SEQ + (size_t)z * 64 * 4096;
  const u16* B = VT + (size_t)col0 * SEQ + (size_t)z * 64 * 4096;
  f32x4 acc[4][4];
  gemm1_db(A, B, 64, lds, acc);
  EPILOGUE_IDX
  float* O = Opart + (size_t)z * SEQ * DIM;
#pragma unroll
  for (int mi = 0; mi < 4; ++mi)
#pragma unroll
    for (int ni = 0; ni < 4; ++ni)
#pragma unroll
      for (int r = 0; r < 4; ++r) {
        int row = row0 + wm * 64 + mi * 16 + q * 4 + r;
        int col = col0 + wn * 64 + ni * 16 + lr;
        O[(size_t)row * DIM + col] = acc[mi][ni][r];
      }
}

__global__ __launch_bounds__(256) void o_reduce_kernel(const float* __restrict__ Op,
                                                       float* __restrict__ O) {
  const size_t N = (size_t)SEQ * DIM;
  size_t i = ((size_t)blockIdx.x * 256 + threadIdx.x) * 4;
  float4 a = *(const float4*)(Op + i);
  float4 b = *(const float4*)(Op + N + i);
  float4 rr;
  rr.x = a.x + b.x;
  rr.y = a.y + b.y;
  rr.z = a.z + b.z;
  rr.w = a.w + b.w;
  *(float4*)(O + i) = rr;
}

// ---------- launch ----------
extern "C" void kernel_launch(void* const* d_in, const int* in_sizes, int n_in,
                              void* d_out, int out_size, void* d_ws, size_t ws_size,
                              hipStream_t stream) {
  const float* X = (const float*)d_in[0];
  const float* Wq = (const float*)d_in[1];
  const float* Wk = (const float*)d_in[2];
  const float* Wv = (const float*)d_in[3];

  const size_t MB = 1024 * 1024;
  char* w = (char*)d_ws;
  u16* Xh = (u16*)(w + 0 * MB);    // 8 MB
  u16* Xl = (u16*)(w + 8 * MB);    // 8 MB
  u16* WqhT = (u16*)(w + 16 * MB); // 2 MB each
  u16* WqlT = (u16*)(w + 18 * MB);
  u16* WkhT = (u16*)(w + 20 * MB);
  u16* WklT = (u16*)(w + 22 * MB);
  u16* WvhT = (u16*)(w + 24 * MB);
  u16* Qh = (u16*)(w + 26 * MB);   // 8 MB each
  u16* Ql = (u16*)(w + 34 * MB);
  u16* Kh = (u16*)(w + 42 * MB);
  u16* Kl = (u16*)(w + 50 * MB);
  u16* VT = (u16*)(w + 58 * MB);   // 8 MB
  float* S = (float*)(w + 66 * MB);    // 64 MB
  u16* P = (u16*)(w + 26 * MB);        // aliases Qh..Kl (dead after s_kernel)
  float* Opart = (float*)(w + 66 * MB);// aliases S (dead after softmax), 32 MB
  // total: 130 MB

  prep_kernel<<<dim3(32, 32, 4), dim3(32, 8), 0, stream>>>(
      X, Wq, Wk, Wv, Xh, Xl, WqhT, WqlT, WkhT, WklT, WvhT);
  qkv_kernel<<<dim3(DIM / 128, SEQ / 128, 3), 256, 0, stream>>>(
      Xh, Xl, WqhT, WqlT, WkhT, WklT, WvhT, Qh, Ql, Kh, Kl, VT);
  s_kernel<<<dim3(SEQ / 256, SEQ / 128), 256, 0, stream>>>(Qh, Ql, Kh, Kl, S);
  softmax_kernel<<<SEQ, 256, 0, stream>>>(S, P);
  o_kernel<<<dim3(DIM / 128, SEQ / 128, 2), 256, 0, stream>>>(P, VT, Opart);
  o_reduce_kernel<<<(SEQ * DIM) / (256 * 4), 256, 0, stream>>>(Opart, (float*)d_out);
}

// Round 12
// 337.454 us; speedup vs baseline: 1.0482x; 1.0482x over previous
//
#include <hip/hip_runtime.h>

typedef unsigned short u16;
typedef __attribute__((ext_vector_type(8))) short bf16x8;
typedef __attribute__((ext_vector_type(4))) float f32x4;

#define SEQ 4096
#define DIM 1024

// ---------- bf16 helpers (OCP bf16 = top 16 bits of fp32, RNE) ----------
__device__ __forceinline__ u16 f2bf(float f) {
  unsigned u = __float_as_uint(f);
  return (u16)((u + 0x7fffu + ((u >> 16) & 1u)) >> 16);
}
__device__ __forceinline__ float bf2f(u16 h) {
  return __uint_as_float(((unsigned)h) << 16);
}

// ---------- async global->LDS, 16B per lane ----------
__device__ __forceinline__ void gload_lds16(const void* g, void* l) {
  __builtin_amdgcn_global_load_lds(
      (const __attribute__((address_space(1))) void*)g,
      (__attribute__((address_space(3))) void*)l, 16, 0, 0);
}

// ---------- tile-packed operand layout (r4/r7-verified: 0 bank conflicts) ----------
// Matrix [R][Kd] stored as 128x32 tiles; tile (rb,kb) at (rb*(Kd/32)+kb)*4096.
// Within tile, 16B slot s = ((r7>>4)<<6) | ((c5>>3)<<4) | (r7&15), elem = c5&7.
__device__ __forceinline__ size_t pkoff(int row, int col, int kd) {
  int tile = (row >> 7) * (kd >> 5) + (col >> 5);
  int r7 = row & 127, c5 = col & 31;
  int slot = ((r7 >> 4) << 6) | ((c5 >> 3) << 4) | (r7 & 15);
  return (size_t)tile * 4096 + (size_t)(slot * 8 + (c5 & 7));
}

// stage one packed 128x32 tile (4096 elems, contiguous) into LDS
__device__ __forceinline__ void stage_tile_pk(const u16* __restrict__ g,
                                              u16* lds, int tid) {
  const int w = tid >> 6;
  gload_lds16(g + (size_t)tid * 8, lds + (size_t)(w * 64) * 8);
  gload_lds16(g + (size_t)(256 + tid) * 8, lds + (size_t)(256 + w * 64) * 8);
}

// ---------- fused 3-pair NT GEMM core, double-buffered (2 x 32KB LDS) ----------
// r7-proven local optimum: 16x16x32, 4x4/wave (16 chains), dbuf, 1 barrier/iter.
// Falsified alternatives: 32x32 shapes (r5,r8), A-direct-to-VGPR (r9),
// single-buffer ratio-4 128x256 tile (r11). Do not revisit without new evidence.
__device__ __forceinline__ void gemm3_db(
    const u16* A0, const u16* A1, const u16* B0, const u16* B1,
    int nkb, u16* lds, f32x4 (&acc)[4][4]) {
  const int tid = threadIdx.x;
  const int w = tid >> 6, l = tid & 63;
  const int wm = w >> 1, wn = w & 1;

#pragma unroll
  for (int mi = 0; mi < 4; ++mi)
#pragma unroll
    for (int ni = 0; ni < 4; ++ni)
      acc[mi][ni] = (f32x4){0.f, 0.f, 0.f, 0.f};

  const int ao = wm * 2048 + l * 8;
  const int bo = wn * 2048 + l * 8;

  stage_tile_pk(A0, lds, tid);
  stage_tile_pk(B0, lds + 4096, tid);
  stage_tile_pk(A1, lds + 8192, tid);
  stage_tile_pk(B1, lds + 12288, tid);

  for (int kb = 0; kb < nkb; ++kb) {
    __syncthreads();
    if (kb + 1 < nkb) {
      u16* nb = lds + ((kb + 1) & 1) * 16384;
      const size_t off = (size_t)(kb + 1) * 4096;
      stage_tile_pk(A0 + off, nb, tid);
      stage_tile_pk(B0 + off, nb + 4096, tid);
      stage_tile_pk(A1 + off, nb + 8192, tid);
      stage_tile_pk(B1 + off, nb + 12288, tid);
    }
    const u16* cb = lds + (kb & 1) * 16384;
    const u16* lA0 = cb;
    const u16* lB0 = cb + 4096;
    const u16* lA1 = cb + 8192;
    const u16* lB1 = cb + 12288;

    bf16x8 a0[4], b0[4];
#pragma unroll
    for (int i = 0; i < 4; ++i) {
      a0[i] = *(const bf16x8*)(lA0 + ao + i * 512);
      b0[i] = *(const bf16x8*)(lB0 + bo + i * 512);
    }
#pragma unroll
    for (int mi = 0; mi < 4; ++mi)
#pragma unroll
      for (int ni = 0; ni < 4; ++ni)
        acc[mi][ni] = __builtin_amdgcn_mfma_f32_16x16x32_bf16(
            a0[mi], b0[ni], acc[mi][ni], 0, 0, 0);
    bf16x8 b1[4];
#pragma unroll
    for (int i = 0; i < 4; ++i) b1[i] = *(const bf16x8*)(lB1 + bo + i * 512);
#pragma unroll
    for (int mi = 0; mi < 4; ++mi)
#pragma unroll
      for (int ni = 0; ni < 4; ++ni)
        acc[mi][ni] = __builtin_amdgcn_mfma_f32_16x16x32_bf16(
            a0[mi], b1[ni], acc[mi][ni], 0, 0, 0);
    bf16x8 a1[4];
#pragma unroll
    for (int i = 0; i < 4; ++i) a1[i] = *(const bf16x8*)(lA1 + ao + i * 512);
#pragma unroll
    for (int mi = 0; mi < 4; ++mi)
#pragma unroll
      for (int ni = 0; ni < 4; ++ni)
        acc[mi][ni] = __builtin_amdgcn_mfma_f32_16x16x32_bf16(
            a1[mi], b0[ni], acc[mi][ni], 0, 0, 0);
  }
  __syncthreads();
}

// ---------- single-pair NT GEMM core, BK=64, double-buffered (2 x 32KB) ----------
__device__ __forceinline__ void gemm1_db(
    const u16* A, const u16* B, int nkb, u16* lds, f32x4 (&acc)[4][4]) {
  const int tid = threadIdx.x;
  const int w = tid >> 6, l = tid & 63;
  const int wm = w >> 1, wn = w & 1;

#pragma unroll
  for (int mi = 0; mi < 4; ++mi)
#pragma unroll
    for (int ni = 0; ni < 4; ++ni)
      acc[mi][ni] = (f32x4){0.f, 0.f, 0.f, 0.f};

  const int ao = wm * 2048 + l * 8;
  const int bo = wn * 2048 + l * 8;
  const int nit = nkb >> 1;

  stage_tile_pk(A, lds, tid);
  stage_tile_pk(A + 4096, lds + 4096, tid);
  stage_tile_pk(B, lds + 8192, tid);
  stage_tile_pk(B + 4096, lds + 12288, tid);

  for (int it = 0; it < nit; ++it) {
    __syncthreads();
    if (it + 1 < nit) {
      u16* nb = lds + ((it + 1) & 1) * 16384;
      const size_t off = (size_t)(it + 1) * 8192;
      stage_tile_pk(A + off, nb, tid);
      stage_tile_pk(A + off + 4096, nb + 4096, tid);
      stage_tile_pk(B + off, nb + 8192, tid);
      stage_tile_pk(B + off + 4096, nb + 12288, tid);
    }
    const u16* cb = lds + (it & 1) * 16384;
#pragma unroll
    for (int ht = 0; ht < 2; ++ht) {
      bf16x8 av[4], bv[4];
#pragma unroll
      for (int i = 0; i < 4; ++i) {
        av[i] = *(const bf16x8*)(cb + ht * 4096 + ao + i * 512);
        bv[i] = *(const bf16x8*)(cb + 8192 + ht * 4096 + bo + i * 512);
      }
#pragma unroll
      for (int mi = 0; mi < 4; ++mi)
#pragma unroll
        for (int ni = 0; ni < 4; ++ni)
          acc[mi][ni] = __builtin_amdgcn_mfma_f32_16x16x32_bf16(
              av[mi], bv[ni], acc[mi][ni], 0, 0, 0);
    }
  }
  __syncthreads();
}

// ---------- epilogue repack: C regs -> packed bf16 h/l via LDS (r10-proven) ----------
__device__ __forceinline__ void epilogue_pack(
    f32x4 (&acc)[4][4], u16* lds, int row0, int col0, int kd,
    u16* __restrict__ H, u16* __restrict__ L) {
  const int tid = threadIdx.x, w = tid >> 6, l = tid & 63;
  const int wm = w >> 1, wn = w & 1, lr = l & 15, q = l >> 4;
  float* lC = (float*)lds;
#pragma unroll
  for (int hh = 0; hh < 2; ++hh) {
    if (wm == hh) {
#pragma unroll
      for (int mi = 0; mi < 4; ++mi)
#pragma unroll
        for (int ni = 0; ni < 4; ++ni)
#pragma unroll
          for (int r = 0; r < 4; ++r)
            lC[(mi * 16 + q * 4 + r) * 132 + wn * 64 + ni * 16 + lr] =
                acc[mi][ni][r];
    }
    __syncthreads();
#pragma unroll
    for (int j = 0; j < 2; ++j) {
      int c = tid + 256 * j;
      int row = c >> 3, c0 = (c & 7) * 16;
      u16 hbuf[16], lbuf[16];
#pragma unroll
      for (int i = 0; i < 16; ++i) {
        float v = lC[row * 132 + c0 + i];
        u16 hv = f2bf(v);
        hbuf[i] = hv;
        lbuf[i] = f2bf(v - bf2f(hv));
      }
      int rg = row0 + hh * 64 + row;
      size_t o0 = pkoff(rg, col0 + c0, kd);
      size_t o1 = pkoff(rg, col0 + c0 + 8, kd);
      *(bf16x8*)(H + o0) = *(bf16x8*)(hbuf);
      *(bf16x8*)(H + o1) = *(bf16x8*)(hbuf + 8);
      if (L) {
        *(bf16x8*)(L + o0) = *(bf16x8*)(lbuf);
        *(bf16x8*)(L + o1) = *(bf16x8*)(lbuf + 8);
      }
    }
    if (hh == 0) __syncthreads();
  }
}

// ---------- epilogue repack fp32: C regs -> row-major float4 stores via LDS ----------
// Same structure as epilogue_pack; replaces 64 scalar stores/thread with
// 8x float4 (64B contiguous per thread, lane-linear).
__device__ __forceinline__ void epilogue_store_f32(
    f32x4 (&acc)[4][4], u16* lds, int row0, int col0, int ld,
    float scale, float* __restrict__ Out) {
  const int tid = threadIdx.x, w = tid >> 6, l = tid & 63;
  const int wm = w >> 1, wn = w & 1, lr = l & 15, q = l >> 4;
  float* lC = (float*)lds;
#pragma unroll
  for (int hh = 0; hh < 2; ++hh) {
    if (wm == hh) {
#pragma unroll
      for (int mi = 0; mi < 4; ++mi)
#pragma unroll
        for (int ni = 0; ni < 4; ++ni)
#pragma unroll
          for (int r = 0; r < 4; ++r)
            lC[(mi * 16 + q * 4 + r) * 132 + wn * 64 + ni * 16 + lr] =
                acc[mi][ni][r];
    }
    __syncthreads();
#pragma unroll
    for (int j = 0; j < 2; ++j) {
      int c = tid + 256 * j;
      int row = c >> 3, c0 = (c & 7) * 16;
      float* dst = Out + (size_t)(row0 + hh * 64 + row) * ld + col0 + c0;
      const float* src = lC + row * 132 + c0;
#pragma unroll
      for (int k = 0; k < 4; ++k) {
        float4 v = *(const float4*)(src + 4 * k);
        v.x *= scale; v.y *= scale; v.z *= scale; v.w *= scale;
        *(float4*)(dst + 4 * k) = v;
      }
    }
    if (hh == 0) __syncthreads();
  }
}

// ---------- kernels ----------

__global__ __launch_bounds__(256) void prep_kernel(
    const float* __restrict__ X,
    const float* __restrict__ W0, const float* __restrict__ W1, const float* __restrict__ W2,
    u16* __restrict__ Xh, u16* __restrict__ Xl,
    u16* __restrict__ H0, u16* __restrict__ L0,
    u16* __restrict__ H1, u16* __restrict__ L1,
    u16* __restrict__ H2) {
  const int z = blockIdx.z;
  const int tx = threadIdx.x, ty = threadIdx.y;
  if (z == 0) {
    int idx = (blockIdx.y * 32 + blockIdx.x) * 256 + ty * 32 + tx;
    int row = idx >> 6;
    int c0 = (idx & 63) * 16;
    u16 h[16], lo[16];
#pragma unroll
    for (int j = 0; j < 4; ++j) {
      float4 x = *(const float4*)(X + (size_t)row * DIM + c0 + j * 4);
      float v;
      v = x.x; h[j*4+0] = f2bf(v); lo[j*4+0] = f2bf(v - bf2f(h[j*4+0]));
      v = x.y; h[j*4+1] = f2bf(v); lo[j*4+1] = f2bf(v - bf2f(h[j*4+1]));
      v = x.z; h[j*4+2] = f2bf(v); lo[j*4+2] = f2bf(v - bf2f(h[j*4+2]));
      v = x.w; h[j*4+3] = f2bf(v); lo[j*4+3] = f2bf(v - bf2f(h[j*4+3]));
    }
    size_t o0 = pkoff(row, c0, DIM);
    size_t o1 = pkoff(row, c0 + 8, DIM);
    *(bf16x8*)(Xh + o0) = *(bf16x8*)(h);
    *(bf16x8*)(Xl + o0) = *(bf16x8*)(lo);
    *(bf16x8*)(Xh + o1) = *(bf16x8*)(h + 8);
    *(bf16x8*)(Xl + o1) = *(bf16x8*)(lo + 8);
    return;
  }
  __shared__ float t[32][33];
  const float* W = (z == 1) ? W0 : (z == 2) ? W1 : W2;
  u16* H = (z == 1) ? H0 : (z == 2) ? H1 : H2;
  u16* L = (z == 1) ? L0 : (z == 2) ? L1 : nullptr;
  const int i0 = blockIdx.y * 32, o0 = blockIdx.x * 32;
#pragma unroll
  for (int m = 0; m < 4; ++m)
    t[ty + 8 * m][tx] = W[(size_t)(i0 + ty + 8 * m) * DIM + o0 + tx];
  __syncthreads();
#pragma unroll
  for (int m = 0; m < 4; ++m) {
    float v = t[tx][ty + 8 * m];
    u16 h = f2bf(v);
    size_t o = pkoff(o0 + ty + 8 * m, i0 + tx, DIM);
    H[o] = h;
    if (L) L[o] = f2bf(v - bf2f(h));
  }
}

// z=0: Q = X Wq (split, packed out)  z=1: K likewise
// z=2: VT = Wv^T X^T (bf16, packed out, rows over DIM, Kd=SEQ)
__global__ __launch_bounds__(256) void qkv_kernel(
    const u16* __restrict__ Xh, const u16* __restrict__ Xl,
    const u16* __restrict__ Wh0, const u16* __restrict__ Wl0,
    const u16* __restrict__ Wh1, const u16* __restrict__ Wl1,
    const u16* __restrict__ Wh2,
    u16* __restrict__ Qh, u16* __restrict__ Ql,
    u16* __restrict__ Kh, u16* __restrict__ Kl,
    u16* __restrict__ VT) {
  __shared__ __align__(16) u16 lds[2 * 4 * 4096];
  const int z = blockIdx.z;
  f32x4 acc[4][4];
  if (z < 2) {
    const u16* Wh = z ? Wh1 : Wh0;
    const u16* Wl = z ? Wl1 : Wl0;
    const int row0 = blockIdx.y * 128, col0 = blockIdx.x * 128;
    gemm3_db(Xh + (size_t)row0 * DIM, Xl + (size_t)row0 * DIM,
             Wh + (size_t)col0 * DIM, Wl + (size_t)col0 * DIM,
             DIM / 32, lds, acc);
    epilogue_pack(acc, lds, row0, col0, DIM, z ? Kh : Qh, z ? Kl : Ql);
  } else {
    const int row0 = blockIdx.x * 128;  // over DIM
    const int col0 = blockIdx.y * 128;  // over SEQ
    gemm1_db(Wh2 + (size_t)row0 * DIM, Xh + (size_t)col0 * DIM,
             DIM / 32, lds, acc);
    epilogue_pack(acc, lds, row0, col0, SEQ, VT, nullptr);
  }
}

// S = (Q K^T) * 1/32, split-precision fused 3-pair, fp32 row-major out
__global__ __launch_bounds__(256) void s_kernel(
    const u16* __restrict__ Qh, const u16* __restrict__ Ql,
    const u16* __restrict__ Kh, const u16* __restrict__ Kl,
    float* __restrict__ S) {
  __shared__ __align__(16) u16 lds[2 * 4 * 4096];
  const int row0 = blockIdx.y * 128, col0 = blockIdx.x * 128;
  f32x4 acc[4][4];
  gemm3_db(Qh + (size_t)row0 * DIM, Ql + (size_t)row0 * DIM,
           Kh + (size_t)col0 * DIM, Kl + (size_t)col0 * DIM,
           DIM / 32, lds, acc);
  epilogue_store_f32(acc, lds, row0, col0, SEQ, 0.03125f, S);
}

// row softmax: S fp32 [4096][4096] -> P bf16 tile-packed (Kd=SEQ)
__global__ __launch_bounds__(256) void softmax_kernel(const float* __restrict__ S,
                                                      u16* __restrict__ P) {
  const int row = blockIdx.x;
  const float* s = S + (size_t)row * SEQ;
  const int tid = threadIdx.x;
  const int c0 = tid * 16;
  float v[16];
  float mx = -3.4e38f;
#pragma unroll
  for (int j = 0; j < 4; ++j) {
    float4 x = *(const float4*)(s + c0 + j * 4);
    v[j * 4 + 0] = x.x; v[j * 4 + 1] = x.y; v[j * 4 + 2] = x.z; v[j * 4 + 3] = x.w;
    mx = fmaxf(mx, fmaxf(fmaxf(x.x, x.y), fmaxf(x.z, x.w)));
  }
#pragma unroll
  for (int off = 32; off; off >>= 1) mx = fmaxf(mx, __shfl_xor(mx, off));
  __shared__ float red[8];
  const int w = tid >> 6, l = tid & 63;
  if (l == 0) red[w] = mx;
  __syncthreads();
  mx = fmaxf(fmaxf(red[0], red[1]), fmaxf(red[2], red[3]));
  float sum = 0.f;
#pragma unroll
  for (int i = 0; i < 16; ++i) {
    v[i] = __expf(v[i] - mx);
    sum += v[i];
  }
#pragma unroll
  for (int off = 32; off; off >>= 1) sum += __shfl_xor(sum, off);
  if (l == 0) red[4 + w] = sum;
  __syncthreads();
  sum = red[4] + red[5] + red[6] + red[7];
  const float inv = 1.f / sum;
  u16 p[16];
#pragma unroll
  for (int i = 0; i < 16; ++i) p[i] = f2bf(v[i] * inv);
  *(bf16x8*)(P + pkoff(row, c0, SEQ)) = *(bf16x8*)(p);
  *(bf16x8*)(P + pkoff(row, c0 + 8, SEQ)) = *(bf16x8*)(p + 8);
}

// O partial = P[:, z*2048:(z+1)*2048] @ V[...]  (split-K=2, packed, BK=64, dbuf)
__global__ __launch_bounds__(256) void o_kernel(const u16* __restrict__ P,
                                                const u16* __restrict__ VT,
                                                float* __restrict__ Opart) {
  __shared__ __align__(16) u16 lds[2 * 4 * 4096];
  const int z = blockIdx.z;
  const int row0 = blockIdx.y * 128, col0 = blockIdx.x * 128;
  const u16* A = P + (size_t)row0 * SEQ + (size_t)z * 64 * 4096;
  const u16* B = VT + (size_t)col0 * SEQ + (size_t)z * 64 * 4096;
  f32x4 acc[4][4];
  gemm1_db(A, B, 64, lds, acc);
  float* O = Opart + (size_t)z * SEQ * DIM;
  epilogue_store_f32(acc, lds, row0, col0, DIM, 1.0f, O);
}

__global__ __launch_bounds__(256) void o_reduce_kernel(const float* __restrict__ Op,
                                                       float* __restrict__ O) {
  const size_t N = (size_t)SEQ * DIM;
  size_t i = ((size_t)blockIdx.x * 256 + threadIdx.x) * 4;
  float4 a = *(const float4*)(Op + i);
  float4 b = *(const float4*)(Op + N + i);
  float4 rr;
  rr.x = a.x + b.x;
  rr.y = a.y + b.y;
  rr.z = a.z + b.z;
  rr.w = a.w + b.w;
  *(float4*)(O + i) = rr;
}

// ---------- launch ----------
extern "C" void kernel_launch(void* const* d_in, const int* in_sizes, int n_in,
                              void* d_out, int out_size, void* d_ws, size_t ws_size,
                              hipStream_t stream) {
  const float* X = (const float*)d_in[0];
  const float* Wq = (const float*)d_in[1];
  const float* Wk = (const float*)d_in[2];
  const float* Wv = (const float*)d_in[3];

  const size_t MB = 1024 * 1024;
  char* w = (char*)d_ws;
  u16* Xh = (u16*)(w + 0 * MB);    // 8 MB
  u16* Xl = (u16*)(w + 8 * MB);    // 8 MB
  u16* WqhT = (u16*)(w + 16 * MB); // 2 MB each
  u16* WqlT = (u16*)(w + 18 * MB);
  u16* WkhT = (u16*)(w + 20 * MB);
  u16* WklT = (u16*)(w + 22 * MB);
  u16* WvhT = (u16*)(w + 24 * MB);
  u16* Qh = (u16*)(w + 26 * MB);   // 8 MB each
  u16* Ql = (u16*)(w + 34 * MB);
  u16* Kh = (u16*)(w + 42 * MB);
  u16* Kl = (u16*)(w + 50 * MB);
  u16* VT = (u16*)(w + 58 * MB);   // 8 MB
  float* S = (float*)(w + 66 * MB);    // 64 MB
  u16* P = (u16*)(w + 26 * MB);        // aliases Qh..Kl (dead after s_kernel)
  float* Opart = (float*)(w + 66 * MB);// aliases S (dead after softmax), 32 MB
  // total: 130 MB

  prep_kernel<<<dim3(32, 32, 4), dim3(32, 8), 0, stream>>>(
      X, Wq, Wk, Wv, Xh, Xl, WqhT, WqlT, WkhT, WklT, WvhT);
  qkv_kernel<<<dim3(DIM / 128, SEQ / 128, 3), 256, 0, stream>>>(
      Xh, Xl, WqhT, WqlT, WkhT, WklT, WvhT, Qh, Ql, Kh, Kl, VT);
  s_kernel<<<dim3(SEQ / 128, SEQ / 128), 256, 0, stream>>>(Qh, Ql, Kh, Kl, S);
  softmax_kernel<<<SEQ, 256, 0, stream>>>(S, P);
  o_kernel<<<dim3(DIM / 128, SEQ / 128, 2), 256, 0, stream>>>(P, VT, Opart);
  o_reduce_kernel<<<(SEQ * DIM) / (256 * 4), 256, 0, stream>>>(Opart, (float*)d_out);
}

// Round 13
// 312.635 us; speedup vs baseline: 1.1314x; 1.0794x over previous
//
#include <hip/hip_runtime.h>

typedef unsigned short u16;
typedef __attribute__((ext_vector_type(8))) short bf16x8;
typedef __attribute__((ext_vector_type(4))) float f32x4;

#define SEQ 4096
#define DIM 1024

// ---------- bf16 helpers (OCP bf16 = top 16 bits of fp32, RNE) ----------
__device__ __forceinline__ u16 f2bf(float f) {
  unsigned u = __float_as_uint(f);
  return (u16)((u + 0x7fffu + ((u >> 16) & 1u)) >> 16);
}
__device__ __forceinline__ float bf2f(u16 h) {
  return __uint_as_float(((unsigned)h) << 16);
}

// ---------- async global->LDS, 16B per lane ----------
__device__ __forceinline__ void gload_lds16(const void* g, void* l) {
  __builtin_amdgcn_global_load_lds(
      (const __attribute__((address_space(1))) void*)g,
      (__attribute__((address_space(3))) void*)l, 16, 0, 0);
}

// ---------- tile-packed operand layout (r4/r7-verified: 0 bank conflicts) ----------
// Matrix [R][Kd] stored as 128x32 tiles; tile (rb,kb) at (rb*(Kd/32)+kb)*4096.
// Within tile, 16B slot s = ((r7>>4)<<6) | ((c5>>3)<<4) | (r7&15), elem = c5&7.
__device__ __forceinline__ size_t pkoff(int row, int col, int kd) {
  int tile = (row >> 7) * (kd >> 5) + (col >> 5);
  int r7 = row & 127, c5 = col & 31;
  int slot = ((r7 >> 4) << 6) | ((c5 >> 3) << 4) | (r7 & 15);
  return (size_t)tile * 4096 + (size_t)(slot * 8 + (c5 & 7));
}

// stage one packed 128x32 tile (4096 elems, contiguous) into LDS
__device__ __forceinline__ void stage_tile_pk(const u16* __restrict__ g,
                                              u16* lds, int tid) {
  const int w = tid >> 6;
  gload_lds16(g + (size_t)tid * 8, lds + (size_t)(w * 64) * 8);
  gload_lds16(g + (size_t)(256 + tid) * 8, lds + (size_t)(256 + w * 64) * 8);
}

// ---------- fused 3-pair NT GEMM core, double-buffered (2 x 32KB LDS) ----------
// r7-proven local optimum: 16x16x32, 4x4/wave (16 chains), dbuf, 1 barrier/iter.
// Falsified alternatives (counter-evidenced): 32x32 shapes (r5,r8), A-direct-
// to-VGPR (r9), single-buffer ratio-4 128x256 tile (r11), fp32 LDS-repack
// epilogue (r12). Do not revisit without new evidence.
__device__ __forceinline__ void gemm3_db(
    const u16* A0, const u16* A1, const u16* B0, const u16* B1,
    int nkb, u16* lds, f32x4 (&acc)[4][4]) {
  const int tid = threadIdx.x;
  const int w = tid >> 6, l = tid & 63;
  const int wm = w >> 1, wn = w & 1;

#pragma unroll
  for (int mi = 0; mi < 4; ++mi)
#pragma unroll
    for (int ni = 0; ni < 4; ++ni)
      acc[mi][ni] = (f32x4){0.f, 0.f, 0.f, 0.f};

  const int ao = wm * 2048 + l * 8;
  const int bo = wn * 2048 + l * 8;

  stage_tile_pk(A0, lds, tid);
  stage_tile_pk(B0, lds + 4096, tid);
  stage_tile_pk(A1, lds + 8192, tid);
  stage_tile_pk(B1, lds + 12288, tid);

  for (int kb = 0; kb < nkb; ++kb) {
    __syncthreads();
    if (kb + 1 < nkb) {
      u16* nb = lds + ((kb + 1) & 1) * 16384;
      const size_t off = (size_t)(kb + 1) * 4096;
      stage_tile_pk(A0 + off, nb, tid);
      stage_tile_pk(B0 + off, nb + 4096, tid);
      stage_tile_pk(A1 + off, nb + 8192, tid);
      stage_tile_pk(B1 + off, nb + 12288, tid);
    }
    const u16* cb = lds + (kb & 1) * 16384;
    const u16* lA0 = cb;
    const u16* lB0 = cb + 4096;
    const u16* lA1 = cb + 8192;
    const u16* lB1 = cb + 12288;

    bf16x8 a0[4], b0[4];
#pragma unroll
    for (int i = 0; i < 4; ++i) {
      a0[i] = *(const bf16x8*)(lA0 + ao + i * 512);
      b0[i] = *(const bf16x8*)(lB0 + bo + i * 512);
    }
#pragma unroll
    for (int mi = 0; mi < 4; ++mi)
#pragma unroll
      for (int ni = 0; ni < 4; ++ni)
        acc[mi][ni] = __builtin_amdgcn_mfma_f32_16x16x32_bf16(
            a0[mi], b0[ni], acc[mi][ni], 0, 0, 0);
    bf16x8 b1[4];
#pragma unroll
    for (int i = 0; i < 4; ++i) b1[i] = *(const bf16x8*)(lB1 + bo + i * 512);
#pragma unroll
    for (int mi = 0; mi < 4; ++mi)
#pragma unroll
      for (int ni = 0; ni < 4; ++ni)
        acc[mi][ni] = __builtin_amdgcn_mfma_f32_16x16x32_bf16(
            a0[mi], b1[ni], acc[mi][ni], 0, 0, 0);
    bf16x8 a1[4];
#pragma unroll
    for (int i = 0; i < 4; ++i) a1[i] = *(const bf16x8*)(lA1 + ao + i * 512);
#pragma unroll
    for (int mi = 0; mi < 4; ++mi)
#pragma unroll
      for (int ni = 0; ni < 4; ++ni)
        acc[mi][ni] = __builtin_amdgcn_mfma_f32_16x16x32_bf16(
            a1[mi], b0[ni], acc[mi][ni], 0, 0, 0);
  }
  __syncthreads();
}

// ---------- single-pair NT GEMM core, BK=64, double-buffered (2 x 32KB) ----------
__device__ __forceinline__ void gemm1_db(
    const u16* A, const u16* B, int nkb, u16* lds, f32x4 (&acc)[4][4]) {
  const int tid = threadIdx.x;
  const int w = tid >> 6, l = tid & 63;
  const int wm = w >> 1, wn = w & 1;

#pragma unroll
  for (int mi = 0; mi < 4; ++mi)
#pragma unroll
    for (int ni = 0; ni < 4; ++ni)
      acc[mi][ni] = (f32x4){0.f, 0.f, 0.f, 0.f};

  const int ao = wm * 2048 + l * 8;
  const int bo = wn * 2048 + l * 8;
  const int nit = nkb >> 1;

  stage_tile_pk(A, lds, tid);
  stage_tile_pk(A + 4096, lds + 4096, tid);
  stage_tile_pk(B, lds + 8192, tid);
  stage_tile_pk(B + 4096, lds + 12288, tid);

  for (int it = 0; it < nit; ++it) {
    __syncthreads();
    if (it + 1 < nit) {
      u16* nb = lds + ((it + 1) & 1) * 16384;
      const size_t off = (size_t)(it + 1) * 8192;
      stage_tile_pk(A + off, nb, tid);
      stage_tile_pk(A + off + 4096, nb + 4096, tid);
      stage_tile_pk(B + off, nb + 8192, tid);
      stage_tile_pk(B + off + 4096, nb + 12288, tid);
    }
    const u16* cb = lds + (it & 1) * 16384;
#pragma unroll
    for (int ht = 0; ht < 2; ++ht) {
      bf16x8 av[4], bv[4];
#pragma unroll
      for (int i = 0; i < 4; ++i) {
        av[i] = *(const bf16x8*)(cb + ht * 4096 + ao + i * 512);
        bv[i] = *(const bf16x8*)(cb + 8192 + ht * 4096 + bo + i * 512);
      }
#pragma unroll
      for (int mi = 0; mi < 4; ++mi)
#pragma unroll
        for (int ni = 0; ni < 4; ++ni)
          acc[mi][ni] = __builtin_amdgcn_mfma_f32_16x16x32_bf16(
              av[mi], bv[ni], acc[mi][ni], 0, 0, 0);
    }
  }
  __syncthreads();
}

// C/D layout (m89/m91 verified): lane l, reg r -> row=(l>>4)*4+r, col=l&15
#define EPILOGUE_IDX                                          \
  const int tid = threadIdx.x, w = tid >> 6, l = tid & 63;    \
  const int wm = w >> 1, wn = w & 1, lr = l & 15, q = l >> 4; \
  (void)tid;

// ---------- epilogue repack: C regs -> packed bf16 h/l via LDS (r10-proven) ----------
// Pays off ONLY for pkoff-scattered u16 outputs (replaces 128 scalar stores);
// fp32 row-major outputs store direct (r12 falsified the fp32 variant).
__device__ __forceinline__ void epilogue_pack(
    f32x4 (&acc)[4][4], u16* lds, int row0, int col0, int kd,
    u16* __restrict__ H, u16* __restrict__ L) {
  const int tid = threadIdx.x, w = tid >> 6, l = tid & 63;
  const int wm = w >> 1, wn = w & 1, lr = l & 15, q = l >> 4;
  float* lC = (float*)lds;
#pragma unroll
  for (int hh = 0; hh < 2; ++hh) {
    if (wm == hh) {
#pragma unroll
      for (int mi = 0; mi < 4; ++mi)
#pragma unroll
        for (int ni = 0; ni < 4; ++ni)
#pragma unroll
          for (int r = 0; r < 4; ++r)
            lC[(mi * 16 + q * 4 + r) * 132 + wn * 64 + ni * 16 + lr] =
                acc[mi][ni][r];
    }
    __syncthreads();
#pragma unroll
    for (int j = 0; j < 2; ++j) {
      int c = tid + 256 * j;
      int row = c >> 3, c0 = (c & 7) * 16;
      u16 hbuf[16], lbuf[16];
#pragma unroll
      for (int i = 0; i < 16; ++i) {
        float v = lC[row * 132 + c0 + i];
        u16 hv = f2bf(v);
        hbuf[i] = hv;
        lbuf[i] = f2bf(v - bf2f(hv));
      }
      int rg = row0 + hh * 64 + row;
      size_t o0 = pkoff(rg, col0 + c0, kd);
      size_t o1 = pkoff(rg, col0 + c0 + 8, kd);
      *(bf16x8*)(H + o0) = *(bf16x8*)(hbuf);
      *(bf16x8*)(H + o1) = *(bf16x8*)(hbuf + 8);
      if (L) {
        *(bf16x8*)(L + o0) = *(bf16x8*)(lbuf);
        *(bf16x8*)(L + o1) = *(bf16x8*)(lbuf + 8);
      }
    }
    if (hh == 0) __syncthreads();
  }
}

// ---------- kernels ----------

__global__ __launch_bounds__(256) void prep_kernel(
    const float* __restrict__ X,
    const float* __restrict__ W0, const float* __restrict__ W1, const float* __restrict__ W2,
    u16* __restrict__ Xh, u16* __restrict__ Xl,
    u16* __restrict__ H0, u16* __restrict__ L0,
    u16* __restrict__ H1, u16* __restrict__ L1,
    u16* __restrict__ H2) {
  const int z = blockIdx.z;
  const int tx = threadIdx.x, ty = threadIdx.y;
  if (z == 0) {
    int idx = (blockIdx.y * 32 + blockIdx.x) * 256 + ty * 32 + tx;
    int row = idx >> 6;
    int c0 = (idx & 63) * 16;
    u16 h[16], lo[16];
#pragma unroll
    for (int j = 0; j < 4; ++j) {
      float4 x = *(const float4*)(X + (size_t)row * DIM + c0 + j * 4);
      float v;
      v = x.x; h[j*4+0] = f2bf(v); lo[j*4+0] = f2bf(v - bf2f(h[j*4+0]));
      v = x.y; h[j*4+1] = f2bf(v); lo[j*4+1] = f2bf(v - bf2f(h[j*4+1]));
      v = x.z; h[j*4+2] = f2bf(v); lo[j*4+2] = f2bf(v - bf2f(h[j*4+2]));
      v = x.w; h[j*4+3] = f2bf(v); lo[j*4+3] = f2bf(v - bf2f(h[j*4+3]));
    }
    size_t o0 = pkoff(row, c0, DIM);
    size_t o1 = pkoff(row, c0 + 8, DIM);
    *(bf16x8*)(Xh + o0) = *(bf16x8*)(h);
    *(bf16x8*)(Xl + o0) = *(bf16x8*)(lo);
    *(bf16x8*)(Xh + o1) = *(bf16x8*)(h + 8);
    *(bf16x8*)(Xl + o1) = *(bf16x8*)(lo + 8);
    return;
  }
  __shared__ float t[32][33];
  const float* W = (z == 1) ? W0 : (z == 2) ? W1 : W2;
  u16* H = (z == 1) ? H0 : (z == 2) ? H1 : H2;
  u16* L = (z == 1) ? L0 : (z == 2) ? L1 : nullptr;
  const int i0 = blockIdx.y * 32, o0 = blockIdx.x * 32;
#pragma unroll
  for (int m = 0; m < 4; ++m)
    t[ty + 8 * m][tx] = W[(size_t)(i0 + ty + 8 * m) * DIM + o0 + tx];
  __syncthreads();
#pragma unroll
  for (int m = 0; m < 4; ++m) {
    float v = t[tx][ty + 8 * m];
    u16 h = f2bf(v);
    size_t o = pkoff(o0 + ty + 8 * m, i0 + tx, DIM);
    H[o] = h;
    if (L) L[o] = f2bf(v - bf2f(h));
  }
}

// z=0: Q = X Wq (split, packed out)  z=1: K likewise
// z=2: VT = Wv^T X^T (bf16, packed out, rows over DIM, Kd=SEQ)
__global__ __launch_bounds__(256) void qkv_kernel(
    const u16* __restrict__ Xh, const u16* __restrict__ Xl,
    const u16* __restrict__ Wh0, const u16* __restrict__ Wl0,
    const u16* __restrict__ Wh1, const u16* __restrict__ Wl1,
    const u16* __restrict__ Wh2,
    u16* __restrict__ Qh, u16* __restrict__ Ql,
    u16* __restrict__ Kh, u16* __restrict__ Kl,
    u16* __restrict__ VT) {
  __shared__ __align__(16) u16 lds[2 * 4 * 4096];
  const int z = blockIdx.z;
  f32x4 acc[4][4];
  if (z < 2) {
    const u16* Wh = z ? Wh1 : Wh0;
    const u16* Wl = z ? Wl1 : Wl0;
    const int row0 = blockIdx.y * 128, col0 = blockIdx.x * 128;
    gemm3_db(Xh + (size_t)row0 * DIM, Xl + (size_t)row0 * DIM,
             Wh + (size_t)col0 * DIM, Wl + (size_t)col0 * DIM,
             DIM / 32, lds, acc);
    epilogue_pack(acc, lds, row0, col0, DIM, z ? Kh : Qh, z ? Kl : Ql);
  } else {
    const int row0 = blockIdx.x * 128;  // over DIM
    const int col0 = blockIdx.y * 128;  // over SEQ
    gemm1_db(Wh2 + (size_t)row0 * DIM, Xh + (size_t)col0 * DIM,
             DIM / 32, lds, acc);
    epilogue_pack(acc, lds, row0, col0, SEQ, VT, nullptr);
  }
}

// S = (Q K^T) * 1/32, split-precision fused 3-pair, fp32 row-major out
__global__ __launch_bounds__(256) void s_kernel(
    const u16* __restrict__ Qh, const u16* __restrict__ Ql,
    const u16* __restrict__ Kh, const u16* __restrict__ Kl,
    float* __restrict__ S) {
  __shared__ __align__(16) u16 lds[2 * 4 * 4096];
  const int row0 = blockIdx.y * 128, col0 = blockIdx.x * 128;
  f32x4 acc[4][4];
  gemm3_db(Qh + (size_t)row0 * DIM, Ql + (size_t)row0 * DIM,
           Kh + (size_t)col0 * DIM, Kl + (size_t)col0 * DIM,
           DIM / 32, lds, acc);
  EPILOGUE_IDX
  const float scale = 0.03125f;  // 1/sqrt(1024)
#pragma unroll
  for (int mi = 0; mi < 4; ++mi)
#pragma unroll
    for (int ni = 0; ni < 4; ++ni)
#pragma unroll
      for (int r = 0; r < 4; ++r) {
        int row = row0 + wm * 64 + mi * 16 + q * 4 + r;
        int col = col0 + wn * 64 + ni * 16 + lr;
        S[(size_t)row * SEQ + col] = acc[mi][ni][r] * scale;
      }
}

// row softmax: S fp32 [4096][4096] -> P bf16 tile-packed (Kd=SEQ)
__global__ __launch_bounds__(256) void softmax_kernel(const float* __restrict__ S,
                                                      u16* __restrict__ P) {
  const int row = blockIdx.x;
  const float* s = S + (size_t)row * SEQ;
  const int tid = threadIdx.x;
  const int c0 = tid * 16;
  float v[16];
  float mx = -3.4e38f;
#pragma unroll
  for (int j = 0; j < 4; ++j) {
    float4 x = *(const float4*)(s + c0 + j * 4);
    v[j * 4 + 0] = x.x; v[j * 4 + 1] = x.y; v[j * 4 + 2] = x.z; v[j * 4 + 3] = x.w;
    mx = fmaxf(mx, fmaxf(fmaxf(x.x, x.y), fmaxf(x.z, x.w)));
  }
#pragma unroll
  for (int off = 32; off; off >>= 1) mx = fmaxf(mx, __shfl_xor(mx, off));
  __shared__ float red[8];
  const int w = tid >> 6, l = tid & 63;
  if (l == 0) red[w] = mx;
  __syncthreads();
  mx = fmaxf(fmaxf(red[0], red[1]), fmaxf(red[2], red[3]));
  float sum = 0.f;
#pragma unroll
  for (int i = 0; i < 16; ++i) {
    v[i] = __expf(v[i] - mx);
    sum += v[i];
  }
#pragma unroll
  for (int off = 32; off; off >>= 1) sum += __shfl_xor(sum, off);
  if (l == 0) red[4 + w] = sum;
  __syncthreads();
  sum = red[4] + red[5] + red[6] + red[7];
  const float inv = 1.f / sum;
  u16 p[16];
#pragma unroll
  for (int i = 0; i < 16; ++i) p[i] = f2bf(v[i] * inv);
  *(bf16x8*)(P + pkoff(row, c0, SEQ)) = *(bf16x8*)(p);
  *(bf16x8*)(P + pkoff(row, c0 + 8, SEQ)) = *(bf16x8*)(p + 8);
}

// O partial = P[:, z*2048:(z+1)*2048] @ V[...]  (split-K=2, packed, BK=64, dbuf)
__global__ __launch_bounds__(256) void o_kernel(const u16* __restrict__ P,
                                                const u16* __restrict__ VT,
                                                float* __restrict__ Opart) {
  __shared__ __align__(16) u16 lds[2 * 4 * 4096];
  const int z = blockIdx.z;
  const int row0 = blockIdx.y * 128, col0 = blockIdx.x * 128;
  const u16* A = P + (size_t)row0 * SEQ + (size_t)z * 64 * 4096;
  const u16* B = VT + (size_t)col0 * SEQ + (size_t)z * 64 * 4096;
  f32x4 acc[4][4];
  gemm1_db(A, B, 64, lds, acc);
  EPILOGUE_IDX
  float* O = Opart + (size_t)z * SEQ * DIM;
#pragma unroll
  for (int mi = 0; mi < 4; ++mi)
#pragma unroll
    for (int ni = 0; ni < 4; ++ni)
#pragma unroll
      for (int r = 0; r < 4; ++r) {
        int row = row0 + wm * 64 + mi * 16 + q * 4 + r;
        int col = col0 + wn * 64 + ni * 16 + lr;
        O[(size_t)row * DIM + col] = acc[mi][ni][r];
      }
}

__global__ __launch_bounds__(256) void o_reduce_kernel(const float* __restrict__ Op,
                                                       float* __restrict__ O) {
  const size_t N = (size_t)SEQ * DIM;
  size_t i = ((size_t)blockIdx.x * 256 + threadIdx.x) * 4;
  float4 a = *(const float4*)(Op + i);
  float4 b = *(const float4*)(Op + N + i);
  float4 rr;
  rr.x = a.x + b.x;
  rr.y = a.y + b.y;
  rr.z = a.z + b.z;
  rr.w = a.w + b.w;
  *(float4*)(O + i) = rr;
}

// ---------- launch ----------
extern "C" void kernel_launch(void* const* d_in, const int* in_sizes, int n_in,
                              void* d_out, int out_size, void* d_ws, size_t ws_size,
                              hipStream_t stream) {
  const float* X = (const float*)d_in[0];
  const float* Wq = (const float*)d_in[1];
  const float* Wk = (const float*)d_in[2];
  const float* Wv = (const float*)d_in[3];

  const size_t MB = 1024 * 1024;
  char* w = (char*)d_ws;
  u16* Xh = (u16*)(w + 0 * MB);    // 8 MB
  u16* Xl = (u16*)(w + 8 * MB);    // 8 MB
  u16* WqhT = (u16*)(w + 16 * MB); // 2 MB each
  u16* WqlT = (u16*)(w + 18 * MB);
  u16* WkhT = (u16*)(w + 20 * MB);
  u16* WklT = (u16*)(w + 22 * MB);
  u16* WvhT = (u16*)(w + 24 * MB);
  u16* Qh = (u16*)(w + 26 * MB);   // 8 MB each
  u16* Ql = (u16*)(w + 34 * MB);
  u16* Kh = (u16*)(w + 42 * MB);
  u16* Kl = (u16*)(w + 50 * MB);
  u16* VT = (u16*)(w + 58 * MB);   // 8 MB
  float* S = (float*)(w + 66 * MB);    // 64 MB
  u16* P = (u16*)(w + 26 * MB);        // aliases Qh..Kl (dead after s_kernel)
  float* Opart = (float*)(w + 66 * MB);// aliases S (dead after softmax), 32 MB
  // total: 130 MB

  prep_kernel<<<dim3(32, 32, 4), dim3(32, 8), 0, stream>>>(
      X, Wq, Wk, Wv, Xh, Xl, WqhT, WqlT, WkhT, WklT, WvhT);
  qkv_kernel<<<dim3(DIM / 128, SEQ / 128, 3), 256, 0, stream>>>(
      Xh, Xl, WqhT, WqlT, WkhT, WklT, WvhT, Qh, Ql, Kh, Kl, VT);
  s_kernel<<<dim3(SEQ / 128, SEQ / 128), 256, 0, stream>>>(Qh, Ql, Kh, Kl, S);
  softmax_kernel<<<SEQ, 256, 0, stream>>>(S, P);
  o_kernel<<<dim3(DIM / 128, SEQ / 128, 2), 256, 0, stream>>>(P, VT, Opart);
  o_reduce_kernel<<<(SEQ * DIM) / (256 * 4), 256, 0, stream>>>(Opart, (float*)d_out);
}